// Round 9
// baseline (188.377 us; speedup 1.0000x reference)
//
#include <hip/hip_runtime.h>

#define INV_T (1.0f / 0.07f)
#define EPSF 1e-8f

typedef __bf16 bf16x8 __attribute__((ext_vector_type(8)));
typedef float f32x4 __attribute__((ext_vector_type(4)));

struct TrueT { static constexpr bool value = true; };
struct FalseT { static constexpr bool value = false; };

__device__ __forceinline__ unsigned short f2b(float x) {
  union { float f; unsigned u; } a; a.f = x;
  return (unsigned short)((a.u + 0x7fffu + ((a.u >> 16) & 1u)) >> 16);
}

// 4 rows per block (one per wave): L2-normalize, cast to bf16.
// Block 0 also zeroes the 2-float loss accumulator.
__global__ __launch_bounds__(256) void norm_kernel(const float* __restrict__ emb,
                                                   unsigned short* __restrict__ ebf,
                                                   float* __restrict__ acc2,
                                                   int D) {
  const int wave = threadIdx.x >> 6;
  const int lane = threadIdx.x & 63;
  const int row = blockIdx.x * 4 + wave;
  const float4* src = (const float4*)(emb + (size_t)row * D);
  float4 v0 = src[lane];
  float4 v1 = src[lane + 64];
  float ss = v0.x * v0.x + v0.y * v0.y + v0.z * v0.z + v0.w * v0.w +
             v1.x * v1.x + v1.y * v1.y + v1.z * v1.z + v1.w * v1.w;
#pragma unroll
  for (int m = 32; m >= 1; m >>= 1) ss += __shfl_xor(ss, m, 64);
  const float r = 1.0f / sqrtf(ss);
  ushort4 o0, o1;
  o0.x = f2b(v0.x * r); o0.y = f2b(v0.y * r); o0.z = f2b(v0.z * r); o0.w = f2b(v0.w * r);
  o1.x = f2b(v1.x * r); o1.y = f2b(v1.y * r); o1.z = f2b(v1.z * r); o1.w = f2b(v1.w * r);
  ushort4* dst = (ushort4*)(ebf + (size_t)row * D);
  dst[lane] = o0;
  dst[lane + 64] = o1;
  if (blockIdx.x == 0 && threadIdx.x < 2) acc2[threadIdx.x] = 0.f;
}

// Upper-block-triangle of sim = e.e^T. 256x256 tile, 8 waves (2Mx4N).
// REGISTER-DIRECT matmul: no LDS staging, no barriers in the K-loop.
// Lane (fr,fk) loads its MFMA fragments straight from global (L2/LLC-resident):
//   A[m]: E[(i0+wm*128+m*16+fr)*D + kt*32 + fk*8 .. +7]   (16B, one line/row)
//   B[n]: E[(j0+wn*64 +n*16+fr)*D + kt*32 + fk*8 .. +7]
// K fully unrolled (template) -> offset immediates, compiler software-pipelines
// with its own counted vmcnt; cross-wave TLP hides L2 latency (no sync points).
// Epilogue (verified r8): LDS combine + private plane stores, no global atomics.
template <int KT>
__global__ __launch_bounds__(512, 2) void sim_kernel(
    const unsigned short* __restrict__ E,   // bf16 normalized, N x D
    const int* __restrict__ labels,         // int32 (harness converts int64)
    float* __restrict__ rp_d, float* __restrict__ rp_n,
    float* __restrict__ cp_d, float* __restrict__ cp_n,
    int D, int N) {
  __shared__ float srd[4][256], srn[4][256];      // row partials per wn
  __shared__ float scd[2][256], scn[2][256];      // col partials per wm

  const int tid = threadIdx.x;
  const int lane = tid & 63;
  const int wave = tid >> 6;               // 0..7
  const int wm = wave >> 2, wn = wave & 3; // 2x4 wave grid: 128x64 per wave
  const int fr = lane & 15;
  const int fk = lane >> 4;

  // XCD-aware swizzle (528 % 8 == 0), then triangular decode
  const int bid = blockIdx.x;
  const int t = (bid & 7) * 66 + (bid >> 3);
  int bb = (int)((sqrtf(8.0f * (float)t + 1.0f) - 1.0f) * 0.5f);
  while ((bb + 1) * (bb + 2) / 2 <= t) ++bb;
  while (bb * (bb + 1) / 2 > t) --bb;
  const int ba = t - bb * (bb + 1) / 2;
  const int i0 = ba * 256;
  const int j0 = bb * 256;
  const bool diag = (i0 == j0);

  f32x4 acc[8][4] = {};

  // per-lane fragment base pointers (constant across K; offsets are immediates)
  const unsigned short* ap[8];
  const unsigned short* bp[4];
#pragma unroll
  for (int m = 0; m < 8; ++m)
    ap[m] = E + (size_t)(i0 + wm * 128 + m * 16 + fr) * D + fk * 8;
#pragma unroll
  for (int n = 0; n < 4; ++n)
    bp[n] = E + (size_t)(j0 + wn * 64 + n * 16 + fr) * D + fk * 8;

#pragma unroll
  for (int kt = 0; kt < KT; ++kt) {
    bf16x8 a[8], b[4];
#pragma unroll
    for (int m = 0; m < 8; ++m) a[m] = *(const bf16x8*)(ap[m] + kt * 32);
#pragma unroll
    for (int n = 0; n < 4; ++n) b[n] = *(const bf16x8*)(bp[n] + kt * 32);
#pragma unroll
    for (int m = 0; m < 8; ++m)
#pragma unroll
      for (int n = 0; n < 4; ++n)
        acc[m][n] = __builtin_amdgcn_mfma_f32_16x16x32_bf16(a[m], b[n], acc[m][n], 0, 0, 0);
  }

  // ---- epilogue: per-wave partials (verified), LDS combine + plane stores ----
  // acc[m][n][r]: i = i0 + wm*128 + m*16 + fk*4 + r ; j = j0 + wn*64 + n*16 + fr
  int jcol[4], labj[4];
#pragma unroll
  for (int n = 0; n < 4; ++n) {
    jcol[n] = j0 + wn * 64 + n * 16 + fr;
    labj[n] = labels[jcol[n]];
  }
  float cd[4] = {0.f, 0.f, 0.f, 0.f}, cn[4] = {0.f, 0.f, 0.f, 0.f};

  auto epilogue = [&](auto DIAG) {
#pragma unroll
    for (int m = 0; m < 8; ++m) {
      float pdm[4] = {0.f, 0.f, 0.f, 0.f}, pnm[4] = {0.f, 0.f, 0.f, 0.f};
      const int ibase = i0 + wm * 128 + m * 16 + fk * 4;
      int li[4];
#pragma unroll
      for (int r = 0; r < 4; ++r) li[r] = labels[ibase + r];
#pragma unroll
      for (int n = 0; n < 4; ++n) {
#pragma unroll
        for (int r = 0; r < 4; ++r) {
          const float s = acc[m][n][r] * INV_T;
          const float es = __expf(s);
          if (DIAG.value) {
            if (jcol[n] != ibase + r) {
              pdm[r] += es;
              if (li[r] == labj[n] && s > 0.0f) pnm[r] += es;
            }
          } else {
            pdm[r] += es;
            cd[n] += es;
            if (li[r] == labj[n] && s > 0.0f) { pnm[r] += es; cn[n] += es; }
          }
        }
      }
#pragma unroll
      for (int sh = 1; sh < 16; sh <<= 1) {
#pragma unroll
        for (int r = 0; r < 4; ++r) {
          pdm[r] += __shfl_xor(pdm[r], sh, 64);
          pnm[r] += __shfl_xor(pnm[r], sh, 64);
        }
      }
      if (fr == 0) {
        const int rbase = wm * 128 + m * 16 + fk * 4;
#pragma unroll
        for (int r = 0; r < 4; ++r) {
          srd[wn][rbase + r] = pdm[r];
          srn[wn][rbase + r] = pnm[r];
        }
      }
    }
  };

  if (diag) epilogue(TrueT{}); else epilogue(FalseT{});

  if (!diag) {
    // col partials: j depends on (n, fr) only; reduce over fk (lanes xor 16,32)
#pragma unroll
    for (int sh = 16; sh < 64; sh <<= 1) {
#pragma unroll
      for (int n = 0; n < 4; ++n) {
        cd[n] += __shfl_xor(cd[n], sh, 64);
        cn[n] += __shfl_xor(cn[n], sh, 64);
      }
    }
    if (fk == 0) {
#pragma unroll
      for (int n = 0; n < 4; ++n) {
        scd[wm][wn * 64 + n * 16 + fr] = cd[n];
        scn[wm][wn * 64 + n * 16 + fr] = cn[n];
      }
    }
  }

  __syncthreads();
  const int t2 = tid & 255;
  if (tid < 256) {
    rp_d[(size_t)bb * N + i0 + t2] = srd[0][t2] + srd[1][t2] + srd[2][t2] + srd[3][t2];
    if (!diag) cp_d[(size_t)ba * N + j0 + t2] = scd[0][t2] + scd[1][t2];
  } else {
    rp_n[(size_t)bb * N + i0 + t2] = srn[0][t2] + srn[1][t2] + srn[2][t2] + srn[3][t2];
    if (!diag) cp_n[(size_t)ba * N + j0 + t2] = scn[0][t2] + scn[1][t2];
  }
}

// Per-row: den = sum of 32 planes (rowpart for p>=ba_i, colpart below);
// loss_i; block reduce; 2 atomicAdds into acc2.
__global__ __launch_bounds__(256) void reduce_kernel(
    const float* __restrict__ rp_d, const float* __restrict__ rp_n,
    const float* __restrict__ cp_d, const float* __restrict__ cp_n,
    float* __restrict__ acc2, int N, int NB) {
  const int tid = threadIdx.x;
  const int i = blockIdx.x * 256 + tid;
  const int bai = i >> 8;
  float d = 0.f, n = 0.f;
  for (int p = 0; p < NB; ++p) {
    d += (p >= bai) ? rp_d[(size_t)p * N + i] : cp_d[(size_t)p * N + i];
    n += (p >= bai) ? rp_n[(size_t)p * N + i] : cp_n[(size_t)p * N + i];
  }
  float sum = 0.f, cnt = 0.f;
  if (n > 0.f && d > 0.f) {
    sum = logf(d + EPSF) - logf(n);
    cnt = 1.f;
  }
#pragma unroll
  for (int m = 32; m >= 1; m >>= 1) {
    sum += __shfl_xor(sum, m, 64);
    cnt += __shfl_xor(cnt, m, 64);
  }
  __shared__ float s1[4], s2[4];
  if ((tid & 63) == 0) { s1[tid >> 6] = sum; s2[tid >> 6] = cnt; }
  __syncthreads();
  if (tid == 0) {
    atomicAdd(&acc2[0], s1[0] + s1[1] + s1[2] + s1[3]);
    atomicAdd(&acc2[1], s2[0] + s2[1] + s2[2] + s2[3]);
  }
}

__global__ void final_kernel(const float* __restrict__ acc2, float* __restrict__ out) {
  const float S = acc2[0], C = acc2[1];
  out[0] = (C > 0.f) ? fabsf(S / C) : 0.f;
}

extern "C" void kernel_launch(void* const* d_in, const int* in_sizes, int n_in,
                              void* d_out, int out_size, void* d_ws, size_t ws_size,
                              hipStream_t stream) {
  const float* emb = (const float*)d_in[0];
  const int* labels = (const int*)d_in[1];
  float* out = (float*)d_out;

  const int N = in_sizes[1];          // 8192
  const int D = in_sizes[0] / N;      // 512
  const int NB = N / 256;             // 32

  char* ws = (char*)d_ws;
  unsigned short* ebf = (unsigned short*)ws;            // N*D*2 = 8 MB
  size_t off = (size_t)N * D * 2;
  float* rp_d = (float*)(ws + off); off += (size_t)NB * N * 4;   // 1 MB each
  float* rp_n = (float*)(ws + off); off += (size_t)NB * N * 4;
  float* cp_d = (float*)(ws + off); off += (size_t)NB * N * 4;
  float* cp_n = (float*)(ws + off); off += (size_t)NB * N * 4;
  float* acc2 = (float*)(ws + off);

  norm_kernel<<<N / 4, 256, 0, stream>>>(emb, ebf, acc2, D);
  const int tri = NB * (NB + 1) / 2;            // 528
  sim_kernel<16><<<tri, 512, 0, stream>>>(ebf, labels, rp_d, rp_n, cp_d, cp_n,
                                          D, N);
  reduce_kernel<<<N / 256, 256, 0, stream>>>(rp_d, rp_n, cp_d, cp_n, acc2, N, NB);
  final_kernel<<<1, 1, 0, stream>>>(acc2, out);
}

// Round 10
// 106.844 us; speedup vs baseline: 1.7631x; 1.7631x over previous
//
#include <hip/hip_runtime.h>

#define INV_T (1.0f / 0.07f)
#define EPSF 1e-8f

typedef __bf16 bf16x8 __attribute__((ext_vector_type(8)));
typedef float f32x4 __attribute__((ext_vector_type(4)));

struct TrueT { static constexpr bool value = true; };
struct FalseT { static constexpr bool value = false; };

__device__ __forceinline__ unsigned short f2b(float x) {
  union { float f; unsigned u; } a; a.f = x;
  return (unsigned short)((a.u + 0x7fffu + ((a.u >> 16) & 1u)) >> 16);
}

__device__ __forceinline__ void gld16(const void* g, void* l) {
  __builtin_amdgcn_global_load_lds(
      (const __attribute__((address_space(1))) unsigned int*)g,
      (__attribute__((address_space(3))) unsigned int*)l, 16, 0, 0);
}

// 4 rows per block (one per wave): L2-normalize, cast to bf16, zero num/den.
__global__ __launch_bounds__(256) void norm_kernel(const float* __restrict__ emb,
                                                   unsigned short* __restrict__ ebf,
                                                   float* __restrict__ num,
                                                   float* __restrict__ den,
                                                   int D) {
  const int wave = threadIdx.x >> 6;
  const int lane = threadIdx.x & 63;
  const int row = blockIdx.x * 4 + wave;
  const float4* src = (const float4*)(emb + (size_t)row * D);
  float4 v0 = src[lane];
  float4 v1 = src[lane + 64];
  float ss = v0.x * v0.x + v0.y * v0.y + v0.z * v0.z + v0.w * v0.w +
             v1.x * v1.x + v1.y * v1.y + v1.z * v1.z + v1.w * v1.w;
#pragma unroll
  for (int m = 32; m >= 1; m >>= 1) ss += __shfl_xor(ss, m, 64);
  const float r = 1.0f / sqrtf(ss);
  ushort4 o0, o1;
  o0.x = f2b(v0.x * r); o0.y = f2b(v0.y * r); o0.z = f2b(v0.z * r); o0.w = f2b(v0.w * r);
  o1.x = f2b(v1.x * r); o1.y = f2b(v1.y * r); o1.z = f2b(v1.z * r); o1.w = f2b(v1.w * r);
  ushort4* dst = (ushort4*)(ebf + (size_t)row * D);
  dst[lane] = o0;
  dst[lane + 64] = o1;
  if (lane == 0) { num[row] = 0.f; den[row] = 0.f; }
}

// Upper-block-triangle of sim = e.e^T. 256x256 tile, BK=32, 8 waves (2Mx4N),
// 2-phase double-buffer, 64KB LDS (r7-verified machinery, bit-identical).
// GRID BALANCE: 512 blocks = 2 exact rounds on 256 CUs.
//   blocks 0..15  : TWO diagonal tiles each (dispatched first -> overlap)
//   blocks 16..511: one off-diagonal tile, XCD-chunked over 496 = 8*62
__global__ __launch_bounds__(512, 2) void sim_kernel(
    const unsigned short* __restrict__ E,   // bf16 normalized, N x D
    const int* __restrict__ labels,         // int32 (harness converts int64)
    float* __restrict__ num, float* __restrict__ den,
    int D, int kTiles) {
  __shared__ unsigned short lds[2][2][256 * 32];  // [buf][A/B], 16KB each, 64KB

  const int tid = threadIdx.x;
  const int lane = tid & 63;
  const int wave = tid >> 6;               // 0..7
  const int wm = wave >> 2, wn = wave & 3; // 2x4 wave grid: 128x64 per wave
  const int fr = lane & 15;
  const int fk = lane >> 4;

  // per-thread constant LDS fragment byte offsets (swizzle XOR is fr-only)
  const int swz = ((fr >> 1) & 3) << 4;
  const int cbk = (fk * 16) ^ swz;
  int aoff[8], boff[4];
#pragma unroll
  for (int m = 0; m < 8; ++m) aoff[m] = (wm * 128 + m * 16 + fr) * 64 + cbk;
#pragma unroll
  for (int n = 0; n < 4; ++n) boff[n] = (wn * 64 + n * 16 + fr) * 64 + cbk;

  // ---- one full tile: K-loop + epilogue (r7-verified) ----
  auto do_tile = [&](int ba, int bb) {
    const int i0 = ba * 256;
    const int j0 = bb * 256;
    const bool diag = (ba == bb);

    f32x4 acc[8][4] = {};

    auto stage = [&](int buf, int kt) {
      const int kbase = kt * 32;
#pragma unroll
      for (int c = 0; c < 2; ++c) {
        const int lo = c * 8192 + tid * 16;            // byte offset in 16KB tile
        const int row = lo >> 6;                       // 64B per row
        const int scb = (lo & 63) ^ (((row >> 1) & 3) << 4);
        const unsigned short* gA = E + (size_t)(i0 + row) * D + kbase + (scb >> 1);
        const unsigned short* gB = E + (size_t)(j0 + row) * D + kbase + (scb >> 1);
        gld16(gA, &lds[buf][0][lo >> 1]);
        gld16(gB, &lds[buf][1][lo >> 1]);
      }
    };

    auto compute = [&](int cb) {
      const char* Ab = (const char*)&lds[cb][0][0];
      const char* Bb = (const char*)&lds[cb][1][0];
      bf16x8 a[8], b[4];
#pragma unroll
      for (int m = 0; m < 8; ++m) a[m] = *(const bf16x8*)(Ab + aoff[m]);
#pragma unroll
      for (int n = 0; n < 4; ++n) b[n] = *(const bf16x8*)(Bb + boff[n]);
      __builtin_amdgcn_s_setprio(1);
#pragma unroll
      for (int m = 0; m < 8; ++m)
#pragma unroll
        for (int n = 0; n < 4; ++n)
          acc[m][n] = __builtin_amdgcn_mfma_f32_16x16x32_bf16(a[m], b[n], acc[m][n], 0, 0, 0);
      __builtin_amdgcn_s_setprio(0);
    };

    stage(0, 0);
    asm volatile("s_waitcnt vmcnt(0)" ::: "memory");
    __builtin_amdgcn_s_barrier();

    int cur = 0;
    for (int kt = 0; kt < kTiles; ++kt) {
      if (kt + 1 < kTiles) stage(cur ^ 1, kt + 1);
      compute(cur);
      asm volatile("s_waitcnt vmcnt(0) lgkmcnt(0)" ::: "memory");
      __builtin_amdgcn_s_barrier();
      cur ^= 1;
    }

    // epilogue: per-row partials + atomics (r7-verified)
    int jcol[4], labj[4];
#pragma unroll
    for (int n = 0; n < 4; ++n) {
      jcol[n] = j0 + wn * 64 + n * 16 + fr;
      labj[n] = labels[jcol[n]];
    }
    float cd[4] = {0.f, 0.f, 0.f, 0.f}, cn[4] = {0.f, 0.f, 0.f, 0.f};

    auto epilogue = [&](auto DIAG) {
#pragma unroll
      for (int m = 0; m < 8; ++m) {
        float pdm[4] = {0.f, 0.f, 0.f, 0.f}, pnm[4] = {0.f, 0.f, 0.f, 0.f};
        const int ibase = i0 + wm * 128 + m * 16 + fk * 4;
        int li[4];
#pragma unroll
        for (int r = 0; r < 4; ++r) li[r] = labels[ibase + r];
#pragma unroll
        for (int n = 0; n < 4; ++n) {
#pragma unroll
          for (int r = 0; r < 4; ++r) {
            const float s = acc[m][n][r] * INV_T;
            const float es = __expf(s);
            if (DIAG.value) {
              if (jcol[n] != ibase + r) {
                pdm[r] += es;
                if (li[r] == labj[n] && s > 0.0f) pnm[r] += es;
              }
            } else {
              pdm[r] += es;
              cd[n] += es;
              if (li[r] == labj[n] && s > 0.0f) { pnm[r] += es; cn[n] += es; }
            }
          }
        }
#pragma unroll
        for (int sh = 1; sh < 16; sh <<= 1) {
#pragma unroll
          for (int r = 0; r < 4; ++r) {
            pdm[r] += __shfl_xor(pdm[r], sh, 64);
            pnm[r] += __shfl_xor(pnm[r], sh, 64);
          }
        }
        if (fr == 0) {
#pragma unroll
          for (int r = 0; r < 4; ++r) {
            atomicAdd(&den[ibase + r], pdm[r]);
            atomicAdd(&num[ibase + r], pnm[r]);
          }
        }
      }
    };

    if (diag) epilogue(TrueT{}); else epilogue(FalseT{});

    if (!diag) {
#pragma unroll
      for (int sh = 16; sh < 64; sh <<= 1) {
#pragma unroll
        for (int n = 0; n < 4; ++n) {
          cd[n] += __shfl_xor(cd[n], sh, 64);
          cn[n] += __shfl_xor(cn[n], sh, 64);
        }
      }
      if (fk == 0) {
#pragma unroll
        for (int n = 0; n < 4; ++n) {
          atomicAdd(&den[jcol[n]], cd[n]);
          atomicAdd(&num[jcol[n]], cn[n]);
        }
      }
    }
  };

  const int bid = blockIdx.x;
  if (bid < 16) {
    // two diagonal tiles, sequential (K-loop ends fully drained -> LDS reuse safe)
    do_tile(2 * bid, 2 * bid);
    __builtin_amdgcn_s_barrier();
    do_tile(2 * bid + 1, 2 * bid + 1);
  } else {
    const int b = bid - 16;                    // 0..495
    const int bs = (b & 7) * 62 + (b >> 3);    // XCD chunk (496 = 8*62)
    // off-diag decode: bs = bb*(bb-1)/2 + ba, ba < bb
    int bb = (int)((1.0f + sqrtf(8.0f * (float)bs + 1.0f)) * 0.5f);
    while (bb * (bb - 1) / 2 > bs) --bb;
    while ((bb + 1) * bb / 2 <= bs) ++bb;
    const int ba = bs - bb * (bb - 1) / 2;
    do_tile(ba, bb);
  }
}

// Final scalar: loss_i = log(den+eps) - log(num) over valid rows; mean; abs.
__global__ __launch_bounds__(256) void loss_kernel(const float* __restrict__ num,
                                                   const float* __restrict__ den,
                                                   float* __restrict__ out, int N) {
  const int tid = threadIdx.x;
  float sum = 0.f, cnt = 0.f;
  for (int i = tid; i < N; i += 256) {
    const float n = num[i], d = den[i];
    if (n > 0.f && d > 0.f) {
      sum += logf(d + EPSF) - logf(n);
      cnt += 1.f;
    }
  }
#pragma unroll
  for (int m = 32; m >= 1; m >>= 1) {
    sum += __shfl_xor(sum, m, 64);
    cnt += __shfl_xor(cnt, m, 64);
  }
  __shared__ float s1[4], s2[4];
  if ((tid & 63) == 0) { s1[tid >> 6] = sum; s2[tid >> 6] = cnt; }
  __syncthreads();
  if (tid == 0) {
    const float S = s1[0] + s1[1] + s1[2] + s1[3];
    const float C = s2[0] + s2[1] + s2[2] + s2[3];
    out[0] = (C > 0.f) ? fabsf(S / C) : 0.f;
  }
}

extern "C" void kernel_launch(void* const* d_in, const int* in_sizes, int n_in,
                              void* d_out, int out_size, void* d_ws, size_t ws_size,
                              hipStream_t stream) {
  const float* emb = (const float*)d_in[0];
  const int* labels = (const int*)d_in[1];
  float* out = (float*)d_out;

  const int N = in_sizes[1];          // 8192
  const int D = in_sizes[0] / N;      // 512

  unsigned short* ebf = (unsigned short*)d_ws;                 // N*D bf16 = 8 MB
  float* num = (float*)((char*)d_ws + (size_t)N * D * 2);      // N f32
  float* den = num + N;                                        // N f32

  norm_kernel<<<N / 4, 256, 0, stream>>>(emb, ebf, num, den, D);
  sim_kernel<<<512, 512, 0, stream>>>(ebf, labels, num, den, D, D / 32);
  loss_kernel<<<1, 256, 0, stream>>>(num, den, out, N);
}

// Round 11
// 91.876 us; speedup vs baseline: 2.0503x; 1.1629x over previous
//
#include <hip/hip_runtime.h>

#define INV_T (1.0f / 0.07f)
#define EPSF 1e-8f

typedef __bf16 bf16x8 __attribute__((ext_vector_type(8)));
typedef float f32x4 __attribute__((ext_vector_type(4)));

struct TrueT { static constexpr bool value = true; };
struct FalseT { static constexpr bool value = false; };

__device__ __forceinline__ unsigned short f2b(float x) {
  union { float f; unsigned u; } a; a.f = x;
  return (unsigned short)((a.u + 0x7fffu + ((a.u >> 16) & 1u)) >> 16);
}

__device__ __forceinline__ void gld16(const void* g, void* l) {
  __builtin_amdgcn_global_load_lds(
      (const __attribute__((address_space(1))) unsigned int*)g,
      (__attribute__((address_space(3))) unsigned int*)l, 16, 0, 0);
}

// 4 rows per block (one per wave): L2-normalize, cast to bf16, zero num/den.
__global__ __launch_bounds__(256) void norm_kernel(const float* __restrict__ emb,
                                                   unsigned short* __restrict__ ebf,
                                                   float* __restrict__ num,
                                                   float* __restrict__ den,
                                                   int D) {
  const int wave = threadIdx.x >> 6;
  const int lane = threadIdx.x & 63;
  const int row = blockIdx.x * 4 + wave;
  const float4* src = (const float4*)(emb + (size_t)row * D);
  float4 v0 = src[lane];
  float4 v1 = src[lane + 64];
  float ss = v0.x * v0.x + v0.y * v0.y + v0.z * v0.z + v0.w * v0.w +
             v1.x * v1.x + v1.y * v1.y + v1.z * v1.z + v1.w * v1.w;
#pragma unroll
  for (int m = 32; m >= 1; m >>= 1) ss += __shfl_xor(ss, m, 64);
  const float r = 1.0f / sqrtf(ss);
  ushort4 o0, o1;
  o0.x = f2b(v0.x * r); o0.y = f2b(v0.y * r); o0.z = f2b(v0.z * r); o0.w = f2b(v0.w * r);
  o1.x = f2b(v1.x * r); o1.y = f2b(v1.y * r); o1.z = f2b(v1.z * r); o1.w = f2b(v1.w * r);
  ushort4* dst = (ushort4*)(ebf + (size_t)row * D);
  dst[lane] = o0;
  dst[lane + 64] = o1;
  if (lane == 0) { num[row] = 0.f; den[row] = 0.f; }
}

// Upper-block-triangle of sim = e.e^T. 128x128 tile, BK=32, 4 waves (2x2).
// OCCUPANCY-FIRST: acc[4][4]=64 regs, __launch_bounds__(256,3) caps regs so
// 3 blocks (12 waves) co-reside per CU -> cross-block overlap hides the
// per-iteration vmcnt drain (m97/m114 regime). Simple 2-phase K-loop.
// r3-verified stage/swizzle/epilogue; XCD-chunked triangular grid (2080=8*260).
template <int D, int KT>
__global__ __launch_bounds__(256, 3) void sim_kernel(
    const unsigned short* __restrict__ E,   // bf16 normalized, N x D
    const int* __restrict__ labels,         // int32 (harness converts int64)
    float* __restrict__ num, float* __restrict__ den) {
  __shared__ unsigned short lds[2][2][128 * 32];  // [buf][A/B], 8KB each, 32KB

  const int tid = threadIdx.x;
  const int lane = tid & 63;
  const int wave = tid >> 6;               // 0..3
  const int wm = wave >> 1, wn = wave & 1; // 2x2 wave grid: 64x64 per wave
  const int fr = lane & 15;
  const int fk = lane >> 4;

  // XCD chunking (2080 = 8*260), then triangular decode t = bb*(bb+1)/2 + ba
  const int bid = blockIdx.x;
  const int t = (bid & 7) * 260 + (bid >> 3);
  int bb = (int)((sqrtf(8.0f * (float)t + 1.0f) - 1.0f) * 0.5f);
  while ((bb + 1) * (bb + 2) / 2 <= t) ++bb;
  while (bb * (bb + 1) / 2 > t) --bb;
  const int ba = t - bb * (bb + 1) / 2;
  const int i0 = ba * 128;
  const int j0 = bb * 128;
  const bool diag = (i0 == j0);

  f32x4 acc[4][4] = {};

  // ds_read base offsets; frag m/n at +m*1024 (immediate offsets in ds_read)
  const int arow0 = wm * 64 + fr;
  const int brow0 = wn * 64 + fr;
  const int aoff0 = arow0 * 64 + ((fk * 16) ^ (((arow0 >> 1) & 3) << 4));
  const int boff0 = brow0 * 64 + ((fk * 16) ^ (((brow0 >> 1) & 3) << 4));

  // staging base pointers (c=0, kt=0); c=1 adds 64 rows, kt adds 32 elems
  const int srow0 = tid >> 2;                       // row for c=0
  const int scb = ((tid * 16) & 63) ^ (((srow0 >> 1) & 3) << 4);
  const unsigned short* gA0 = E + (size_t)(i0 + srow0) * D + (scb >> 1);
  const unsigned short* gB0 = E + (size_t)(j0 + srow0) * D + (scb >> 1);
  const int ldst0 = tid * 16;                       // LDS byte offset, c=0

  auto stage = [&](int buf, int kt) {
    const int ke = kt * 32;
    gld16(gA0 + ke, (char*)&lds[buf][0][0] + ldst0);
    gld16(gA0 + 64 * D + ke, (char*)&lds[buf][0][0] + 4096 + ldst0);
    gld16(gB0 + ke, (char*)&lds[buf][1][0] + ldst0);
    gld16(gB0 + 64 * D + ke, (char*)&lds[buf][1][0] + 4096 + ldst0);
  };

  auto compute = [&](int cb) {
    const char* Ab = (const char*)&lds[cb][0][0] + aoff0;
    const char* Bb = (const char*)&lds[cb][1][0] + boff0;
    bf16x8 a[4], b[4];
#pragma unroll
    for (int m = 0; m < 4; ++m) a[m] = *(const bf16x8*)(Ab + m * 1024);
#pragma unroll
    for (int n = 0; n < 4; ++n) b[n] = *(const bf16x8*)(Bb + n * 1024);
    __builtin_amdgcn_s_setprio(1);
#pragma unroll
    for (int m = 0; m < 4; ++m)
#pragma unroll
      for (int n = 0; n < 4; ++n)
        acc[m][n] = __builtin_amdgcn_mfma_f32_16x16x32_bf16(a[m], b[n], acc[m][n], 0, 0, 0);
    __builtin_amdgcn_s_setprio(0);
  };

  stage(0, 0);
  asm volatile("s_waitcnt vmcnt(0)" ::: "memory");
  __builtin_amdgcn_s_barrier();

  int cur = 0;
#pragma unroll 1
  for (int kt = 0; kt < KT; ++kt) {
    if (kt + 1 < KT) stage(cur ^ 1, kt + 1);
    compute(cur);
    asm volatile("s_waitcnt vmcnt(0) lgkmcnt(0)" ::: "memory");
    __builtin_amdgcn_s_barrier();
    cur ^= 1;
  }

  // ---- epilogue (r3-verified): per-row partials + atomics ----
  // acc[m][n][r]: i = i0 + wm*64 + m*16 + fk*4 + r ; j = j0 + wn*64 + n*16 + fr
  int jcol[4], labj[4];
#pragma unroll
  for (int n = 0; n < 4; ++n) {
    jcol[n] = j0 + wn * 64 + n * 16 + fr;
    labj[n] = labels[jcol[n]];
  }
  float cd[4] = {0.f, 0.f, 0.f, 0.f}, cn[4] = {0.f, 0.f, 0.f, 0.f};

  auto epilogue = [&](auto DIAG) {
#pragma unroll
    for (int m = 0; m < 4; ++m) {
      float pdm[4] = {0.f, 0.f, 0.f, 0.f}, pnm[4] = {0.f, 0.f, 0.f, 0.f};
      const int ibase = i0 + wm * 64 + m * 16 + fk * 4;
      int li[4];
#pragma unroll
      for (int r = 0; r < 4; ++r) li[r] = labels[ibase + r];
#pragma unroll
      for (int n = 0; n < 4; ++n) {
#pragma unroll
        for (int r = 0; r < 4; ++r) {
          const float s = acc[m][n][r] * INV_T;
          const float es = __expf(s);
          if (DIAG.value) {
            if (jcol[n] != ibase + r) {
              pdm[r] += es;
              if (li[r] == labj[n] && s > 0.0f) pnm[r] += es;
            }
          } else {
            pdm[r] += es;
            cd[n] += es;
            if (li[r] == labj[n] && s > 0.0f) { pnm[r] += es; cn[n] += es; }
          }
        }
      }
#pragma unroll
      for (int sh = 1; sh < 16; sh <<= 1) {
#pragma unroll
        for (int r = 0; r < 4; ++r) {
          pdm[r] += __shfl_xor(pdm[r], sh, 64);
          pnm[r] += __shfl_xor(pnm[r], sh, 64);
        }
      }
      if (fr == 0) {
#pragma unroll
        for (int r = 0; r < 4; ++r) {
          atomicAdd(&den[ibase + r], pdm[r]);
          atomicAdd(&num[ibase + r], pnm[r]);
        }
      }
    }
  };

  if (diag) epilogue(TrueT{}); else epilogue(FalseT{});

  if (!diag) {
    // col partials: j depends on (n, fr) only; reduce over fk (lanes xor 16,32)
#pragma unroll
    for (int sh = 16; sh < 64; sh <<= 1) {
#pragma unroll
      for (int n = 0; n < 4; ++n) {
        cd[n] += __shfl_xor(cd[n], sh, 64);
        cn[n] += __shfl_xor(cn[n], sh, 64);
      }
    }
    if (fk == 0) {
#pragma unroll
      for (int n = 0; n < 4; ++n) {
        atomicAdd(&den[jcol[n]], cd[n]);
        atomicAdd(&num[jcol[n]], cn[n]);
      }
    }
  }
}

// Final scalar: loss_i = log(den+eps) - log(num) over valid rows; mean; abs.
__global__ __launch_bounds__(256) void loss_kernel(const float* __restrict__ num,
                                                   const float* __restrict__ den,
                                                   float* __restrict__ out, int N) {
  const int tid = threadIdx.x;
  float sum = 0.f, cnt = 0.f;
  for (int i = tid; i < N; i += 256) {
    const float n = num[i], d = den[i];
    if (n > 0.f && d > 0.f) {
      sum += logf(d + EPSF) - logf(n);
      cnt += 1.f;
    }
  }
#pragma unroll
  for (int m = 32; m >= 1; m >>= 1) {
    sum += __shfl_xor(sum, m, 64);
    cnt += __shfl_xor(cnt, m, 64);
  }
  __shared__ float s1[4], s2[4];
  if ((tid & 63) == 0) { s1[tid >> 6] = sum; s2[tid >> 6] = cnt; }
  __syncthreads();
  if (tid == 0) {
    const float S = s1[0] + s1[1] + s1[2] + s1[3];
    const float C = s2[0] + s2[1] + s2[2] + s2[3];
    out[0] = (C > 0.f) ? fabsf(S / C) : 0.f;
  }
}

extern "C" void kernel_launch(void* const* d_in, const int* in_sizes, int n_in,
                              void* d_out, int out_size, void* d_ws, size_t ws_size,
                              hipStream_t stream) {
  const float* emb = (const float*)d_in[0];
  const int* labels = (const int*)d_in[1];
  float* out = (float*)d_out;

  const int N = in_sizes[1];          // 8192
  const int D = in_sizes[0] / N;      // 512

  unsigned short* ebf = (unsigned short*)d_ws;                 // N*D bf16 = 8 MB
  float* num = (float*)((char*)d_ws + (size_t)N * D * 2);      // N f32
  float* den = num + N;                                        // N f32

  norm_kernel<<<N / 4, 256, 0, stream>>>(emb, ebf, num, den, D);
  const int nb = N / 128;                       // 64
  const int tri = nb * (nb + 1) / 2;            // 2080
  sim_kernel<512, 16><<<tri, 256, 0, stream>>>(ebf, labels, num, den);
  loss_kernel<<<1, 256, 0, stream>>>(num, den, out, N);
}

// Round 12
// 78.734 us; speedup vs baseline: 2.3926x; 1.1669x over previous
//
#include <hip/hip_runtime.h>

#define INV_T (1.0f / 0.07f)
#define EPSF 1e-8f

typedef __bf16 bf16x8 __attribute__((ext_vector_type(8)));
typedef float f32x4 __attribute__((ext_vector_type(4)));

struct TrueT { static constexpr bool value = true; };
struct FalseT { static constexpr bool value = false; };

__device__ __forceinline__ unsigned short f2b(float x) {
  union { float f; unsigned u; } a; a.f = x;
  return (unsigned short)((a.u + 0x7fffu + ((a.u >> 16) & 1u)) >> 16);
}

__device__ __forceinline__ void gld16(const void* g, void* l) {
  __builtin_amdgcn_global_load_lds(
      (const __attribute__((address_space(1))) unsigned int*)g,
      (__attribute__((address_space(3))) unsigned int*)l, 16, 0, 0);
}

// 4 rows per block (one per wave): L2-normalize, cast to bf16, zero num/den.
__global__ __launch_bounds__(256) void norm_kernel(const float* __restrict__ emb,
                                                   unsigned short* __restrict__ ebf,
                                                   float* __restrict__ num,
                                                   float* __restrict__ den,
                                                   int D) {
  const int wave = threadIdx.x >> 6;
  const int lane = threadIdx.x & 63;
  const int row = blockIdx.x * 4 + wave;
  const float4* src = (const float4*)(emb + (size_t)row * D);
  float4 v0 = src[lane];
  float4 v1 = src[lane + 64];
  float ss = v0.x * v0.x + v0.y * v0.y + v0.z * v0.z + v0.w * v0.w +
             v1.x * v1.x + v1.y * v1.y + v1.z * v1.z + v1.w * v1.w;
#pragma unroll
  for (int m = 32; m >= 1; m >>= 1) ss += __shfl_xor(ss, m, 64);
  const float r = 1.0f / sqrtf(ss);
  ushort4 o0, o1;
  o0.x = f2b(v0.x * r); o0.y = f2b(v0.y * r); o0.z = f2b(v0.z * r); o0.w = f2b(v0.w * r);
  o1.x = f2b(v1.x * r); o1.y = f2b(v1.y * r); o1.z = f2b(v1.z * r); o1.w = f2b(v1.w * r);
  ushort4* dst = (ushort4*)(ebf + (size_t)row * D);
  dst[lane] = o0;
  dst[lane + 64] = o1;
  if (lane == 0) { num[row] = 0.f; den[row] = 0.f; }
}

// Upper-block-triangle of sim = e.e^T. 128x128 tile, BK=32, 4 waves (2x2),
// __launch_bounds__(256,3) -> 3 blocks/CU (r11-verified regime).
// K-loop: 3-buffer counted-vmcnt pipeline (r5-verified pattern):
//   stage(t+2); compute(t); vmcnt(4) [t+1 landed, t+2 in flight]; barrier.
// Epilogue: NO shuffle-reduce storm -- lanes scatter pdm/pnm to padded LDS
// (stride-5 words, conflict-free writes), one barrier, 256 consumer threads
// each sum 32 entries and do a single atomicAdd.
template <int D, int KT>
__global__ __launch_bounds__(256, 3) void sim_kernel(
    const unsigned short* __restrict__ E,   // bf16 normalized, N x D
    const int* __restrict__ labels,         // int32 (harness converts int64)
    float* __restrict__ num, float* __restrict__ den) {
  __shared__ __align__(16) char smem[49152];   // 3 x 16KB stage bufs; reused by epilogue
  float* red = (float*)smem;                   // epilogue scatter: 2 x 5120 words (40KB)

  const int tid = threadIdx.x;
  const int lane = tid & 63;
  const int wave = tid >> 6;               // 0..3
  const int wm = wave >> 1, wn = wave & 1; // 2x2 wave grid: 64x64 per wave
  const int fr = lane & 15;
  const int fk = lane >> 4;

  // XCD chunking (2080 = 8*260), then triangular decode t = bb*(bb+1)/2 + ba
  const int bid = blockIdx.x;
  const int t = (bid & 7) * 260 + (bid >> 3);
  int bb = (int)((sqrtf(8.0f * (float)t + 1.0f) - 1.0f) * 0.5f);
  while ((bb + 1) * (bb + 2) / 2 <= t) ++bb;
  while (bb * (bb + 1) / 2 > t) --bb;
  const int ba = t - bb * (bb + 1) / 2;
  const int i0 = ba * 128;
  const int j0 = bb * 128;
  const bool diag = (i0 == j0);

  f32x4 acc[4][4] = {};

  // ds_read base offsets; frag m/n at +m*1024 (immediate offsets in ds_read)
  const int arow0 = wm * 64 + fr;
  const int brow0 = wn * 64 + fr;
  const int aoff0 = arow0 * 64 + ((fk * 16) ^ (((arow0 >> 1) & 3) << 4));
  const int boff0 = brow0 * 64 + ((fk * 16) ^ (((brow0 >> 1) & 3) << 4));

  // staging base pointers (c=0, kt=0); c=1 adds 64 rows, kt adds 32 elems
  const int srow0 = tid >> 2;                       // row for c=0
  const int scb = ((tid * 16) & 63) ^ (((srow0 >> 1) & 3) << 4);
  const unsigned short* gA0 = E + (size_t)(i0 + srow0) * D + (scb >> 1);
  const unsigned short* gB0 = E + (size_t)(j0 + srow0) * D + (scb >> 1);
  const int ldst0 = tid * 16;                       // LDS byte offset, c=0

  auto stage = [&](int buf, int kt) {
    const int ke = kt * 32;
    char* A = smem + buf * 16384;
    char* B = A + 8192;
    gld16(gA0 + ke, A + ldst0);
    gld16(gA0 + 64 * D + ke, A + 4096 + ldst0);
    gld16(gB0 + ke, B + ldst0);
    gld16(gB0 + 64 * D + ke, B + 4096 + ldst0);
  };

  auto compute = [&](int cb) {
    const char* Ab = smem + cb * 16384 + aoff0;
    const char* Bb = smem + cb * 16384 + 8192 + boff0;
    bf16x8 a[4], b[4];
#pragma unroll
    for (int m = 0; m < 4; ++m) a[m] = *(const bf16x8*)(Ab + m * 1024);
#pragma unroll
    for (int n = 0; n < 4; ++n) b[n] = *(const bf16x8*)(Bb + n * 1024);
    __builtin_amdgcn_s_setprio(1);
#pragma unroll
    for (int m = 0; m < 4; ++m)
#pragma unroll
      for (int n = 0; n < 4; ++n)
        acc[m][n] = __builtin_amdgcn_mfma_f32_16x16x32_bf16(a[m], b[n], acc[m][n], 0, 0, 0);
    __builtin_amdgcn_s_setprio(0);
  };

  // prologue: tiles 0,1 staged; wait for tile 0 (8 outstanding -> 4)
  stage(0, 0);
  stage(1, 1);
  asm volatile("s_waitcnt vmcnt(4)" ::: "memory");
  __builtin_amdgcn_s_barrier();

  int cur = 0, sb = 2;
#pragma unroll 1
  for (int kt = 0; kt < KT - 2; ++kt) {
    stage(sb, kt + 2);
    compute(cur);
    asm volatile("s_waitcnt vmcnt(4)" ::: "memory");  // kt+1 landed; kt+2 in flight
    __builtin_amdgcn_s_barrier();
    cur = (cur == 2) ? 0 : cur + 1;
    sb = (sb == 2) ? 0 : sb + 1;
  }
  compute(cur);                                       // kt = KT-2
  asm volatile("s_waitcnt vmcnt(0)" ::: "memory");    // last tile complete
  __builtin_amdgcn_s_barrier();
  cur = (cur == 2) ? 0 : cur + 1;
  compute(cur);                                       // kt = KT-1
  __builtin_amdgcn_s_barrier();                       // all reads done -> smem reusable

  // ---- epilogue ----
  // acc[m][n][r]: i = i0 + wm*64 + m*16 + fk*4 + r ; j = j0 + wn*64 + n*16 + fr
  int jcol[4], labj[4];
#pragma unroll
  for (int n = 0; n < 4; ++n) {
    jcol[n] = j0 + wn * 64 + n * 16 + fr;
    labj[n] = labels[jcol[n]];
  }
  float cd[4] = {0.f, 0.f, 0.f, 0.f}, cn[4] = {0.f, 0.f, 0.f, 0.f};

  auto epilogue = [&](auto DIAG) {
#pragma unroll
    for (int m = 0; m < 4; ++m) {
      float pdm[4] = {0.f, 0.f, 0.f, 0.f}, pnm[4] = {0.f, 0.f, 0.f, 0.f};
      const int ibase = i0 + wm * 64 + m * 16 + fk * 4;
      int li[4];
#pragma unroll
      for (int r = 0; r < 4; ++r) li[r] = labels[ibase + r];
#pragma unroll
      for (int n = 0; n < 4; ++n) {
#pragma unroll
        for (int r = 0; r < 4; ++r) {
          const float s = acc[m][n][r] * INV_T;
          const float es = __expf(s);
          if (DIAG.value) {
            if (jcol[n] != ibase + r) {
              pdm[r] += es;
              if (li[r] == labj[n] && s > 0.0f) pnm[r] += es;
            }
          } else {
            pdm[r] += es;
            cd[n] += es;
            if (li[r] == labj[n] && s > 0.0f) { pnm[r] += es; cn[n] += es; }
          }
        }
      }
      // scatter to padded LDS: word = ((wave*4+m)*64 + lane)*5 + r  (CF writes)
      const int base = ((wave * 4 + m) * 64 + lane) * 5;
#pragma unroll
      for (int r = 0; r < 4; ++r) {
        red[base + r] = pdm[r];
        red[5120 + base + r] = pnm[r];
      }
    }
  };

  if (diag) epilogue(TrueT{}); else epilogue(FalseT{});

  if (!diag) {
    // col partials: j depends on (n, fr) only; reduce over fk (lanes xor 16,32)
#pragma unroll
    for (int sh = 16; sh < 64; sh <<= 1) {
#pragma unroll
      for (int n = 0; n < 4; ++n) {
        cd[n] += __shfl_xor(cd[n], sh, 64);
        cn[n] += __shfl_xor(cn[n], sh, 64);
      }
    }
    if (fk == 0) {
#pragma unroll
      for (int n = 0; n < 4; ++n) {
        atomicAdd(&den[jcol[n]], cd[n]);
        atomicAdd(&num[jcol[n]], cn[n]);
      }
    }
  }

  __syncthreads();
  // consumer: tid<128 -> den rows, tid>=128 -> num rows; 32 summands each
  {
    const int which = tid >> 7;                  // 0: pd->den, 1: pn->num
    const int ri = tid & 127;                    // local row
    const int cwm = ri >> 6, cm = (ri >> 4) & 3, cfk = (ri >> 2) & 3, cr = ri & 3;
    const float* src = red + which * 5120;
    float v = 0.f;
#pragma unroll
    for (int w2 = 0; w2 < 2; ++w2)
#pragma unroll
      for (int f2 = 0; f2 < 16; ++f2)
        v += src[(((cwm * 2 + w2) * 4 + cm) * 64 + cfk * 16 + f2) * 5 + cr];
    atomicAdd((which ? num : den) + i0 + ri, v);
  }
}

// Final scalar: loss_i = log(den+eps) - log(num) over valid rows; mean; abs.
__global__ __launch_bounds__(256) void loss_kernel(const float* __restrict__ num,
                                                   const float* __restrict__ den,
                                                   float* __restrict__ out, int N) {
  const int tid = threadIdx.x;
  float sum = 0.f, cnt = 0.f;
  for (int i = tid; i < N; i += 256) {
    const float n = num[i], d = den[i];
    if (n > 0.f && d > 0.f) {
      sum += logf(d + EPSF) - logf(n);
      cnt += 1.f;
    }
  }
#pragma unroll
  for (int m = 32; m >= 1; m >>= 1) {
    sum += __shfl_xor(sum, m, 64);
    cnt += __shfl_xor(cnt, m, 64);
  }
  __shared__ float s1[4], s2[4];
  if ((tid & 63) == 0) { s1[tid >> 6] = sum; s2[tid >> 6] = cnt; }
  __syncthreads();
  if (tid == 0) {
    const float S = s1[0] + s1[1] + s1[2] + s1[3];
    const float C = s2[0] + s2[1] + s2[2] + s2[3];
    out[0] = (C > 0.f) ? fabsf(S / C) : 0.f;
  }
}

extern "C" void kernel_launch(void* const* d_in, const int* in_sizes, int n_in,
                              void* d_out, int out_size, void* d_ws, size_t ws_size,
                              hipStream_t stream) {
  const float* emb = (const float*)d_in[0];
  const int* labels = (const int*)d_in[1];
  float* out = (float*)d_out;

  const int N = in_sizes[1];          // 8192
  const int D = in_sizes[0] / N;      // 512

  unsigned short* ebf = (unsigned short*)d_ws;                 // N*D bf16 = 8 MB
  float* num = (float*)((char*)d_ws + (size_t)N * D * 2);      // N f32
  float* den = num + N;                                        // N f32

  norm_kernel<<<N / 4, 256, 0, stream>>>(emb, ebf, num, den, D);
  const int nb = N / 128;                       // 64
  const int tri = nb * (nb + 1) / 2;            // 2080
  sim_kernel<512, 16><<<tri, 256, 0, stream>>>(ebf, labels, num, den);
  loss_kernel<<<1, 256, 0, stream>>>(num, den, out, N);
}

// Round 13
// 72.008 us; speedup vs baseline: 2.6161x; 1.0934x over previous
//
#include <hip/hip_runtime.h>

#define INV_T (1.0f / 0.07f)
#define EPSF 1e-8f

typedef float f32x4 __attribute__((ext_vector_type(4)));

struct TrueT { static constexpr bool value = true; };
struct FalseT { static constexpr bool value = false; };

__device__ __forceinline__ void gld16(const void* g, void* l) {
  __builtin_amdgcn_global_load_lds(
      (const __attribute__((address_space(1))) unsigned int*)g,
      (__attribute__((address_space(3))) unsigned int*)l, 16, 0, 0);
}

// 4 rows per block (one per wave): L2-normalize, cast to fp8 e4m3, zero num/den.
__global__ __launch_bounds__(256) void norm_kernel(const float* __restrict__ emb,
                                                   unsigned char* __restrict__ e8,
                                                   float* __restrict__ num,
                                                   float* __restrict__ den,
                                                   int D) {
  const int wave = threadIdx.x >> 6;
  const int lane = threadIdx.x & 63;
  const int row = blockIdx.x * 4 + wave;
  const float4* src = (const float4*)(emb + (size_t)row * D);
  float4 v0 = src[lane];
  float4 v1 = src[lane + 64];
  float ss = v0.x * v0.x + v0.y * v0.y + v0.z * v0.z + v0.w * v0.w +
             v1.x * v1.x + v1.y * v1.y + v1.z * v1.z + v1.w * v1.w;
#pragma unroll
  for (int m = 32; m >= 1; m >>= 1) ss += __shfl_xor(ss, m, 64);
  const float r = 1.0f / sqrtf(ss);
  // pack 4+4 floats into two fp8x4 words (OCP e4m3 on gfx950)
  int w0 = __builtin_amdgcn_cvt_pk_fp8_f32(v0.x * r, v0.y * r, 0, false);
  w0 = __builtin_amdgcn_cvt_pk_fp8_f32(v0.z * r, v0.w * r, w0, true);
  int w1 = __builtin_amdgcn_cvt_pk_fp8_f32(v1.x * r, v1.y * r, 0, false);
  w1 = __builtin_amdgcn_cvt_pk_fp8_f32(v1.z * r, v1.w * r, w1, true);
  unsigned int* dst = (unsigned int*)(e8 + (size_t)row * D);
  dst[lane] = (unsigned int)w0;        // cols 4*lane..4*lane+3
  dst[64 + lane] = (unsigned int)w1;   // cols 256+4*lane..
  if (lane == 0) { num[row] = 0.f; den[row] = 0.f; }
}

// Upper-block-triangle of sim = e.e^T. 128x128 tile, BK=32, 4 waves (2x2),
// __launch_bounds__(256,3) -> 3 blocks/CU (r11/r12-verified regime).
// FP8 e4m3 staging + mfma_f32_16x16x32_fp8_fp8: same MFMA rate as bf16 but
// HALF the LDS bytes (b64 frag reads, 8KB/tile staged) -- attacks the LDS-port
// bound. 32-B LDS rows put b64 reads at the bank-volume floor -> no swizzle,
// linear layout both sides. Fragment k-permutation cancels in e.e^T.
// K-loop: 3-buffer counted-vmcnt (r12-verified shape, 2 loads/tile -> vmcnt(2)).
// Epilogue: r12-verified LDS scatter + 256-consumer single-atomic reduce.
template <int D, int KT>
__global__ __launch_bounds__(256, 3) void sim_kernel(
    const unsigned char* __restrict__ E,    // fp8 normalized, N x D
    const int* __restrict__ labels,         // int32 (harness converts int64)
    float* __restrict__ num, float* __restrict__ den) {
  __shared__ __align__(16) char smem[40960];   // 3 x 8KB stage bufs | 40KB epilogue
  float* red = (float*)smem;                   // epilogue scatter: 2 x 5120 words

  const int tid = threadIdx.x;
  const int lane = tid & 63;
  const int wave = tid >> 6;               // 0..3
  const int wm = wave >> 1, wn = wave & 1; // 2x2 wave grid: 64x64 per wave
  const int fr = lane & 15;
  const int fk = lane >> 4;

  // XCD chunking (2080 = 8*260), then triangular decode t = bb*(bb+1)/2 + ba
  const int bid = blockIdx.x;
  const int t = (bid & 7) * 260 + (bid >> 3);
  int bb = (int)((sqrtf(8.0f * (float)t + 1.0f) - 1.0f) * 0.5f);
  while ((bb + 1) * (bb + 2) / 2 <= t) ++bb;
  while (bb * (bb + 1) / 2 > t) --bb;
  const int ba = t - bb * (bb + 1) / 2;
  const int i0 = ba * 128;
  const int j0 = bb * 128;
  const bool diag = (i0 == j0);

  f32x4 acc[4][4] = {};

  // ds_read byte offsets: row*32 + fk*8, frag m at +m*512 (16 rows)
  const int aoff0 = (wm * 64 + fr) * 32 + fk * 8;
  const int boff0 = (wn * 64 + fr) * 32 + fk * 8;

  // staging: 256 threads x 16B = 4KB = one matrix; row = tid/2, col = (tid&1)*16
  const unsigned char* gA0 = E + (size_t)(i0 + (tid >> 1)) * D + (tid & 1) * 16;
  const unsigned char* gB0 = E + (size_t)(j0 + (tid >> 1)) * D + (tid & 1) * 16;
  const int ldst0 = tid * 16;

  auto stage = [&](int buf, int kt) {
    const int ke = kt * 32;                        // 32 fp8 = 32 bytes per K-tile
    char* A = smem + buf * 8192;
    gld16(gA0 + ke, A + ldst0);
    gld16(gB0 + ke, A + 4096 + ldst0);
  };

  auto compute = [&](int cb) {
    const char* Ab = smem + cb * 8192 + aoff0;
    const char* Bb = smem + cb * 8192 + 4096 + boff0;
    long a[4], b[4];
#pragma unroll
    for (int m = 0; m < 4; ++m) a[m] = *(const long*)(Ab + m * 512);
#pragma unroll
    for (int n = 0; n < 4; ++n) b[n] = *(const long*)(Bb + n * 512);
    __builtin_amdgcn_s_setprio(1);
#pragma unroll
    for (int m = 0; m < 4; ++m)
#pragma unroll
      for (int n = 0; n < 4; ++n)
        acc[m][n] = __builtin_amdgcn_mfma_f32_16x16x32_fp8_fp8(a[m], b[n], acc[m][n], 0, 0, 0);
    __builtin_amdgcn_s_setprio(0);
  };

  // prologue: tiles 0,1 staged (4 outstanding); wait tile 0 (-> 2 left)
  stage(0, 0);
  stage(1, 1);
  asm volatile("s_waitcnt vmcnt(2)" ::: "memory");
  __builtin_amdgcn_s_barrier();

  int cur = 0, sb = 2;
#pragma unroll 1
  for (int kt = 0; kt < KT - 2; ++kt) {
    stage(sb, kt + 2);
    compute(cur);
    asm volatile("s_waitcnt vmcnt(2)" ::: "memory");  // kt+1 landed; kt+2 in flight
    __builtin_amdgcn_s_barrier();
    cur = (cur == 2) ? 0 : cur + 1;
    sb = (sb == 2) ? 0 : sb + 1;
  }
  compute(cur);                                       // kt = KT-2
  asm volatile("s_waitcnt vmcnt(0)" ::: "memory");    // last tile complete
  __builtin_amdgcn_s_barrier();
  cur = (cur == 2) ? 0 : cur + 1;
  compute(cur);                                       // kt = KT-1
  __builtin_amdgcn_s_barrier();                       // all reads done -> smem reusable

  // ---- epilogue (r12-verified) ----
  // acc[m][n][r]: i = i0 + wm*64 + m*16 + fk*4 + r ; j = j0 + wn*64 + n*16 + fr
  int jcol[4], labj[4];
#pragma unroll
  for (int n = 0; n < 4; ++n) {
    jcol[n] = j0 + wn * 64 + n * 16 + fr;
    labj[n] = labels[jcol[n]];
  }
  float cd[4] = {0.f, 0.f, 0.f, 0.f}, cn[4] = {0.f, 0.f, 0.f, 0.f};

  auto epilogue = [&](auto DIAG) {
#pragma unroll
    for (int m = 0; m < 4; ++m) {
      float pdm[4] = {0.f, 0.f, 0.f, 0.f}, pnm[4] = {0.f, 0.f, 0.f, 0.f};
      const int ibase = i0 + wm * 64 + m * 16 + fk * 4;
      int li[4];
#pragma unroll
      for (int r = 0; r < 4; ++r) li[r] = labels[ibase + r];
#pragma unroll
      for (int n = 0; n < 4; ++n) {
#pragma unroll
        for (int r = 0; r < 4; ++r) {
          const float s = acc[m][n][r] * INV_T;
          const float es = __expf(s);
          if (DIAG.value) {
            if (jcol[n] != ibase + r) {
              pdm[r] += es;
              if (li[r] == labj[n] && s > 0.0f) pnm[r] += es;
            }
          } else {
            pdm[r] += es;
            cd[n] += es;
            if (li[r] == labj[n] && s > 0.0f) { pnm[r] += es; cn[n] += es; }
          }
        }
      }
      // scatter to padded LDS: word = ((wave*4+m)*64 + lane)*5 + r
      const int base = ((wave * 4 + m) * 64 + lane) * 5;
#pragma unroll
      for (int r = 0; r < 4; ++r) {
        red[base + r] = pdm[r];
        red[5120 + base + r] = pnm[r];
      }
    }
  };

  if (diag) epilogue(TrueT{}); else epilogue(FalseT{});

  if (!diag) {
    // col partials: j depends on (n, fr) only; reduce over fk (lanes xor 16,32)
#pragma unroll
    for (int sh = 16; sh < 64; sh <<= 1) {
#pragma unroll
      for (int n = 0; n < 4; ++n) {
        cd[n] += __shfl_xor(cd[n], sh, 64);
        cn[n] += __shfl_xor(cn[n], sh, 64);
      }
    }
    if (fk == 0) {
#pragma unroll
      for (int n = 0; n < 4; ++n) {
        atomicAdd(&den[jcol[n]], cd[n]);
        atomicAdd(&num[jcol[n]], cn[n]);
      }
    }
  }

  __syncthreads();
  // consumer: tid<128 -> den rows, tid>=128 -> num rows; 32 summands each
  {
    const int which = tid >> 7;                  // 0: pd->den, 1: pn->num
    const int ri = tid & 127;                    // local row
    const int cwm = ri >> 6, cm = (ri >> 4) & 3, cfk = (ri >> 2) & 3, cr = ri & 3;
    const float* src = red + which * 5120;
    float v = 0.f;
#pragma unroll
    for (int w2 = 0; w2 < 2; ++w2)
#pragma unroll
      for (int f2 = 0; f2 < 16; ++f2)
        v += src[(((cwm * 2 + w2) * 4 + cm) * 64 + cfk * 16 + f2) * 5 + cr];
    atomicAdd((which ? num : den) + i0 + ri, v);
  }
}

// Final scalar: loss_i = log(den+eps) - log(num) over valid rows; mean; abs.
__global__ __launch_bounds__(256) void loss_kernel(const float* __restrict__ num,
                                                   const float* __restrict__ den,
                                                   float* __restrict__ out, int N) {
  const int tid = threadIdx.x;
  float sum = 0.f, cnt = 0.f;
  for (int i = tid; i < N; i += 256) {
    const float n = num[i], d = den[i];
    if (n > 0.f && d > 0.f) {
      sum += logf(d + EPSF) - logf(n);
      cnt += 1.f;
    }
  }
#pragma unroll
  for (int m = 32; m >= 1; m >>= 1) {
    sum += __shfl_xor(sum, m, 64);
    cnt += __shfl_xor(cnt, m, 64);
  }
  __shared__ float s1[4], s2[4];
  if ((tid & 63) == 0) { s1[tid >> 6] = sum; s2[tid >> 6] = cnt; }
  __syncthreads();
  if (tid == 0) {
    const float S = s1[0] + s1[1] + s1[2] + s1[3];
    const float C = s2[0] + s2[1] + s2[2] + s2[3];
    out[0] = (C > 0.f) ? fabsf(S / C) : 0.f;
  }
}

extern "C" void kernel_launch(void* const* d_in, const int* in_sizes, int n_in,
                              void* d_out, int out_size, void* d_ws, size_t ws_size,
                              hipStream_t stream) {
  const float* emb = (const float*)d_in[0];
  const int* labels = (const int*)d_in[1];
  float* out = (float*)d_out;

  const int N = in_sizes[1];          // 8192
  const int D = in_sizes[0] / N;      // 512

  unsigned char* e8 = (unsigned char*)d_ws;                    // N*D fp8 = 4 MB
  float* num = (float*)((char*)d_ws + (size_t)N * D);          // N f32
  float* den = num + N;                                        // N f32

  norm_kernel<<<N / 4, 256, 0, stream>>>(emb, e8, num, den, D);
  const int nb = N / 128;                       // 64
  const int tri = nb * (nb + 1) / 2;            // 2080
  sim_kernel<512, 16><<<tri, 256, 0, stream>>>(e8, labels, num, den);
  loss_kernel<<<1, 256, 0, stream>>>(num, den, out, N);
}

// Round 14
// 55.022 us; speedup vs baseline: 3.4237x; 1.3087x over previous
//
#include <hip/hip_runtime.h>

#define INV_T (1.0f / 0.07f)
#define EPSF 1e-8f

typedef float f32x4 __attribute__((ext_vector_type(4)));
typedef long longx2 __attribute__((ext_vector_type(2)));

struct TrueT { static constexpr bool value = true; };
struct FalseT { static constexpr bool value = false; };

// 4 rows per block (one per wave): L2-normalize, cast to fp8 e4m3, zero num/den/acc2.
__global__ __launch_bounds__(256) void norm_kernel(const float* __restrict__ emb,
                                                   unsigned char* __restrict__ e8,
                                                   float* __restrict__ num,
                                                   float* __restrict__ den,
                                                   float* __restrict__ acc2,
                                                   int D) {
  const int wave = threadIdx.x >> 6;
  const int lane = threadIdx.x & 63;
  const int row = blockIdx.x * 4 + wave;
  const float4* src = (const float4*)(emb + (size_t)row * D);
  float4 v0 = src[lane];
  float4 v1 = src[lane + 64];
  float ss = v0.x * v0.x + v0.y * v0.y + v0.z * v0.z + v0.w * v0.w +
             v1.x * v1.x + v1.y * v1.y + v1.z * v1.z + v1.w * v1.w;
#pragma unroll
  for (int m = 32; m >= 1; m >>= 1) ss += __shfl_xor(ss, m, 64);
  const float r = 1.0f / sqrtf(ss);
  int w0 = __builtin_amdgcn_cvt_pk_fp8_f32(v0.x * r, v0.y * r, 0, false);
  w0 = __builtin_amdgcn_cvt_pk_fp8_f32(v0.z * r, v0.w * r, w0, true);
  int w1 = __builtin_amdgcn_cvt_pk_fp8_f32(v1.x * r, v1.y * r, 0, false);
  w1 = __builtin_amdgcn_cvt_pk_fp8_f32(v1.z * r, v1.w * r, w1, true);
  unsigned int* dst = (unsigned int*)(e8 + (size_t)row * D);
  dst[lane] = (unsigned int)w0;
  dst[64 + lane] = (unsigned int)w1;
  if (lane == 0) { num[row] = 0.f; den[row] = 0.f; }
  if (blockIdx.x == 0 && threadIdx.x < 2) acc2[threadIdx.x] = 0.f;
}

// Upper-block-triangle of sim = e.e^T. 128x128 tile, 4 waves (2x2), (256,3)
// -> 3 blocks/CU. FP8 kk-PAIR LDS LAYOUT: per row (64B super-tile, BK=64),
// 16B unit u holds [kk0: G[k+u*8..+7] | kk1: G[k+32+u*8..+7]] -- one
// ds_read_b128 per fragment serves TWO MFMA k-steps, start banks
// (row&1)*16+fk*4 span all 32 banks -> conflict-free (r13's b64 reads were
// 4-way on 16 banks, 14.4M conflict cycles). Layout needs 8B interleave ->
// reg staging (T14 async split): loads(t+2) issued before compute(t),
// ds_writes(t+1) after; compiler counted-vmcnt; 1 lgkm+barrier per super-tile.
template <int D, int KT>   // KT = D/64 super-tiles
__global__ __launch_bounds__(256, 3) void sim_kernel(
    const unsigned char* __restrict__ E,    // fp8 normalized, N x D
    const int* __restrict__ labels,         // int32 (harness converts int64)
    float* __restrict__ num, float* __restrict__ den) {
  __shared__ __align__(16) char smem[40960];   // 2 x 16KB stage bufs | 40KB epilogue
  float* red = (float*)smem;

  const int tid = threadIdx.x;
  const int lane = tid & 63;
  const int wave = tid >> 6;               // 0..3
  const int wm = wave >> 1, wn = wave & 1; // 2x2 wave grid: 64x64 per wave
  const int fr = lane & 15;
  const int fk = lane >> 4;

  // XCD chunking (2080 = 8*260), then triangular decode t = bb*(bb+1)/2 + ba
  const int bid = blockIdx.x;
  const int t = (bid & 7) * 260 + (bid >> 3);
  int bb = (int)((sqrtf(8.0f * (float)t + 1.0f) - 1.0f) * 0.5f);
  while ((bb + 1) * (bb + 2) / 2 <= t) ++bb;
  while (bb * (bb + 1) / 2 > t) --bb;
  const int ba = t - bb * (bb + 1) / 2;
  const int i0 = ba * 128;
  const int j0 = bb * 128;
  const bool diag = (i0 == j0);

  f32x4 acc[4][4] = {};

  // frag read offsets: (row)*64 + fk*16, frag m at +m*1024 (16 rows)
  const int aoff0 = (wm * 64 + fr) * 64 + fk * 16;
  const int boff0 = (wn * 64 + fr) * 64 + fk * 16;

  // staging thread map: row = tid>>2 (plus h*64), u = tid&3
  const unsigned char* gA = E + (size_t)(i0 + (tid >> 2)) * D + (tid & 3) * 8;
  const unsigned char* gB = E + (size_t)(j0 + (tid >> 2)) * D + (tid & 3) * 8;
  const int woff = (tid >> 2) * 64 + (tid & 3) * 16;

  long Pa[8], Pb[8];

  auto loadR = [&](int st, long (&P)[8]) {
    const int kb = st * 64;
    P[0] = *(const long*)(gA + kb);
    P[1] = *(const long*)(gA + kb + 32);
    P[2] = *(const long*)(gA + (size_t)64 * D + kb);
    P[3] = *(const long*)(gA + (size_t)64 * D + kb + 32);
    P[4] = *(const long*)(gB + kb);
    P[5] = *(const long*)(gB + kb + 32);
    P[6] = *(const long*)(gB + (size_t)64 * D + kb);
    P[7] = *(const long*)(gB + (size_t)64 * D + kb + 32);
  };

  auto dsW = [&](int buf, const long (&P)[8]) {
    char* base = smem + buf * 16384;
    *(longx2*)(base + woff) = longx2{P[0], P[1]};
    *(longx2*)(base + woff + 4096) = longx2{P[2], P[3]};
    *(longx2*)(base + 8192 + woff) = longx2{P[4], P[5]};
    *(longx2*)(base + 8192 + woff + 4096) = longx2{P[6], P[7]};
  };

  auto compute = [&](int buf) {
    const char* Ab = smem + buf * 16384 + aoff0;
    const char* Bb = smem + buf * 16384 + 8192 + boff0;
    longx2 A[4], B[4];
#pragma unroll
    for (int m = 0; m < 4; ++m) A[m] = *(const longx2*)(Ab + m * 1024);
#pragma unroll
    for (int n = 0; n < 4; ++n) B[n] = *(const longx2*)(Bb + n * 1024);
    __builtin_amdgcn_s_setprio(1);
#pragma unroll
    for (int kk = 0; kk < 2; ++kk)
#pragma unroll
      for (int m = 0; m < 4; ++m)
#pragma unroll
        for (int n = 0; n < 4; ++n)
          acc[m][n] = __builtin_amdgcn_mfma_f32_16x16x32_fp8_fp8(A[m][kk], B[n][kk], acc[m][n], 0, 0, 0);
    __builtin_amdgcn_s_setprio(0);
  };

#define BARRIER_SEQ                                           \
  asm volatile("s_waitcnt lgkmcnt(0)" ::: "memory");          \
  __builtin_amdgcn_sched_barrier(0);                          \
  __builtin_amdgcn_s_barrier();                               \
  __builtin_amdgcn_sched_barrier(0);

  // prologue: super-tile 0 staged to buf0; tile 1 loaded to regs
  loadR(0, Pa);
  dsW(0, Pa);            // compiler inserts counted vmcnt before writes
  loadR(1, Pb);
  BARRIER_SEQ;

#pragma unroll
  for (int st = 0; st < KT; ++st) {
    if (st & 1) {
      if (st + 2 < KT) loadR(st + 2, Pb);
      compute(1);
      if (st + 1 < KT) { dsW(0, Pa); BARRIER_SEQ; }
    } else {
      if (st + 2 < KT) loadR(st + 2, Pa);
      compute(0);
      if (st + 1 < KT) { dsW(1, Pb); BARRIER_SEQ; }
    }
  }
  __syncthreads();       // full drain; smem reusable for epilogue

  // ---- epilogue (r12/r13-verified math; scatter with lane^(m<<2) XOR) ----
  // acc[m][n][r]: i = i0 + wm*64 + m*16 + fk*4 + r ; j = j0 + wn*64 + n*16 + fr
  int jcol[4], labj[4];
#pragma unroll
  for (int n = 0; n < 4; ++n) {
    jcol[n] = j0 + wn * 64 + n * 16 + fr;
    labj[n] = labels[jcol[n]];
  }
  float cd[4] = {0.f, 0.f, 0.f, 0.f}, cn[4] = {0.f, 0.f, 0.f, 0.f};

  auto epilogue = [&](auto DIAG) {
#pragma unroll
    for (int m = 0; m < 4; ++m) {
      float pdm[4] = {0.f, 0.f, 0.f, 0.f}, pnm[4] = {0.f, 0.f, 0.f, 0.f};
      const int ibase = i0 + wm * 64 + m * 16 + fk * 4;
      int li[4];
#pragma unroll
      for (int r = 0; r < 4; ++r) li[r] = labels[ibase + r];
#pragma unroll
      for (int n = 0; n < 4; ++n) {
#pragma unroll
        for (int r = 0; r < 4; ++r) {
          const float s = acc[m][n][r] * INV_T;
          const float es = __expf(s);
          if (DIAG.value) {
            if (jcol[n] != ibase + r) {
              pdm[r] += es;
              if (li[r] == labj[n] && s > 0.0f) pnm[r] += es;
            }
          } else {
            pdm[r] += es;
            cd[n] += es;
            if (li[r] == labj[n] && s > 0.0f) { pnm[r] += es; cn[n] += es; }
          }
        }
      }
      // scatter: word = ((wave*4+m)*64 + (lane ^ (m<<2)))*5 + r
      const int base = ((wave * 4 + m) * 64 + (lane ^ (m << 2))) * 5;
#pragma unroll
      for (int r = 0; r < 4; ++r) {
        red[base + r] = pdm[r];
        red[5120 + base + r] = pnm[r];
      }
    }
  };

  if (diag) epilogue(TrueT{}); else epilogue(FalseT{});

  if (!diag) {
    // col partials: j depends on (n, fr) only; reduce over fk (lanes xor 16,32)
#pragma unroll
    for (int sh = 16; sh < 64; sh <<= 1) {
#pragma unroll
      for (int n = 0; n < 4; ++n) {
        cd[n] += __shfl_xor(cd[n], sh, 64);
        cn[n] += __shfl_xor(cn[n], sh, 64);
      }
    }
    if (fk == 0) {
#pragma unroll
      for (int n = 0; n < 4; ++n) {
        atomicAdd(&den[jcol[n]], cd[n]);
        atomicAdd(&num[jcol[n]], cn[n]);
      }
    }
  }

  __syncthreads();
  // consumer: tid<128 -> den rows, tid>=128 -> num rows; 32 summands each
  {
    const int which = tid >> 7;                  // 0: pd->den, 1: pn->num
    const int ri = tid & 127;                    // local row
    const int cwm = ri >> 6, cm = (ri >> 4) & 3, cfk = (ri >> 2) & 3, cr = ri & 3;
    const float* src = red + which * 5120;
    float v = 0.f;
#pragma unroll
    for (int w2 = 0; w2 < 2; ++w2)
#pragma unroll
      for (int f2 = 0; f2 < 16; ++f2)
        v += src[(((cwm * 2 + w2) * 4 + cm) * 64 + ((cfk * 16 + f2) ^ (cm << 2))) * 5 + cr];
    atomicAdd((which ? num : den) + i0 + ri, v);
  }
}

// 16 blocks: per-row loss, block-reduce, atomicAdd into acc2[0]=sum, [1]=count.
__global__ __launch_bounds__(256) void loss_reduce(const float* __restrict__ num,
                                                   const float* __restrict__ den,
                                                   float* __restrict__ acc2, int N) {
  const int tid = threadIdx.x;
  int i = blockIdx.x * 512 + tid;
  float sum = 0.f, cnt = 0.f;
#pragma unroll
  for (int k = 0; k < 2; ++k, i += 256) {
    const float n = num[i], d = den[i];
    if (n > 0.f && d > 0.f) {
      sum += logf(d + EPSF) - logf(n);
      cnt += 1.f;
    }
  }
#pragma unroll
  for (int m = 32; m >= 1; m >>= 1) {
    sum += __shfl_xor(sum, m, 64);
    cnt += __shfl_xor(cnt, m, 64);
  }
  __shared__ float s1[4], s2[4];
  if ((tid & 63) == 0) { s1[tid >> 6] = sum; s2[tid >> 6] = cnt; }
  __syncthreads();
  if (tid == 0) {
    atomicAdd(&acc2[0], s1[0] + s1[1] + s1[2] + s1[3]);
    atomicAdd(&acc2[1], s2[0] + s2[1] + s2[2] + s2[3]);
  }
}

__global__ void final_kernel(const float* __restrict__ acc2, float* __restrict__ out) {
  const float S = acc2[0], C = acc2[1];
  out[0] = (C > 0.f) ? fabsf(S / C) : 0.f;
}

extern "C" void kernel_launch(void* const* d_in, const int* in_sizes, int n_in,
                              void* d_out, int out_size, void* d_ws, size_t ws_size,
                              hipStream_t stream) {
  const float* emb = (const float*)d_in[0];
  const int* labels = (const int*)d_in[1];
  float* out = (float*)d_out;

  const int N = in_sizes[1];          // 8192
  const int D = in_sizes[0] / N;      // 512

  unsigned char* e8 = (unsigned char*)d_ws;                    // N*D fp8 = 4 MB
  float* num = (float*)((char*)d_ws + (size_t)N * D);          // N f32
  float* den = num + N;                                        // N f32
  float* acc2 = den + N;                                       // 2 f32

  norm_kernel<<<N / 4, 256, 0, stream>>>(emb, e8, num, den, acc2, D);
  const int nb = N / 128;                       // 64
  const int tri = nb * (nb + 1) / 2;            // 2080
  sim_kernel<512, 8><<<tri, 256, 0, stream>>>(e8, labels, num, den);
  loss_reduce<<<N / 512, 256, 0, stream>>>(num, den, acc2, N);
  final_kernel<<<1, 1, 0, stream>>>(acc2, out);
}